// Round 9
// baseline (386.692 us; speedup 1.0000x reference)
//
#include <hip/hip_runtime.h>
#include <hip/hip_bf16.h>
#include <hip/hip_cooperative_groups.h>
#include <math.h>

namespace cg = cooperative_groups;

#define NN 20000
#define NE 320000
#define BN_EPS 1e-5f

// ws layout (fp32 neigh again)
#define NEIGH_BYTES (NN * 16 * 4)              // 1,280,000
#define BNACC_OFF   NEIGH_BYTES
#define Y_OFF       (NEIGH_BYTES + 128)
#define A3_OFF      (Y_OFF + NN * 16 * 4)      // 32 KB swizzled We2^T (bf16)

typedef __bf16 bf16x8 __attribute__((ext_vector_type(8)));
typedef float  f32x4  __attribute__((ext_vector_type(4)));

union BF8 { bf16x8 v; unsigned short us[8]; unsigned int ui[4]; };

__device__ __forceinline__ unsigned short f2bf(float f) {
    unsigned int u = __builtin_bit_cast(unsigned int, f);
    u += 0x7FFFu + ((u >> 16) & 1u);   // RNE
    return (unsigned short)(u >> 16);
}
__device__ __forceinline__ float bf2f(unsigned short s) {
    unsigned int u = ((unsigned int)s) << 16;
    return __builtin_bit_cast(float, u);
}
__device__ __forceinline__ unsigned int pack2bf(float a, float b) {
    return (unsigned int)f2bf(a) | ((unsigned int)f2bf(b) << 16);
}

// Shared edge-tile worker (r6 math, verified absmax 1.03e-2).
// a3 = swizzled We2^T fragments, either LDS (fallback) or global (cooperative).
template <typename PTR>
__device__ __forceinline__ void edge_tiles(
    const float* __restrict__ h_neigh, const float* __restrict__ efeat,
    const int* __restrict__ src, const int* __restrict__ dst,
    const float* __restrict__ We1, const float* __restrict__ be1,
    const float* __restrict__ be2, float* __restrict__ neigh,
    PTR a3, int t, int nblocks, int myblock)
{
    const int L = t & 63, wv = t >> 6;
    const int lo16 = L & 15, q = L >> 4;
    const int qc = q & 1;
    const bool qlow = (q < 2);
    const bool qhi1 = ((q >> 1) != 0);   // target-side chunk select

    // We1^T A-frags (hi/lo) in registers, bias in K-padding slot k=16
    BF8 w1h[4], w1l[4];
#pragma unroll
    for (int c = 0; c < 4; c++) {
#pragma unroll
        for (int j = 0; j < 8; j++) {
            float w;
            if (q < 2)                 w = We1[(q * 8 + j) * 64 + c * 16 + lo16];
            else if (q == 2 && j == 0) w = be1[c * 16 + lo16];
            else                       w = 0.f;
            unsigned short h = f2bf(w);
            w1h[c].us[j] = h;
            w1l[c].us[j] = f2bf(w - bf2f(h));
        }
    }

    BF8 be2T;
#pragma unroll
    for (int j = 0; j < 8; j++) {
        float bv = be2[(qc * 8 + j) * 16 + lo16];
        be2T.us[j] = qlow ? f2bf(bv) : (unsigned short)0;
    }

    // bpermute source-lane byte addresses: src lane = ((q&1)*2 + (tt>>1))*16 + e
    const int addrA = (((q & 1) * 2 + 0) * 16 + lo16) * 4;
    const int addrB = (((q & 1) * 2 + 1) * 16 + lo16) * 4;

    for (int bt = myblock; bt < NE / 64; bt += nblocks) {
        int e = bt * 64 + wv * 16 + lo16;
        int se = src[e];
        int de = dst[e];

        float xr[16];
        {
            const float4* xp = (const float4*)(h_neigh + (size_t)se * 16);
#pragma unroll
            for (int k4 = 0; k4 < 4; k4++) {
                float4 a = xp[k4];
                xr[k4*4+0] = a.x; xr[k4*4+1] = a.y; xr[k4*4+2] = a.z; xr[k4*4+3] = a.w;
            }
        }

        BF8 a2h, a2l;
        {
            const float4* ep = (const float4*)(efeat + (size_t)e * 16 + qc * 8);
            float4 e0 = ep[0], e1 = ep[1];
            float ev[8] = {e0.x, e0.y, e0.z, e0.w, e1.x, e1.y, e1.z, e1.w};
#pragma unroll
            for (int j = 0; j < 8; j++) {
                if (qlow) {
                    unsigned short h = f2bf(ev[j]);
                    a2h.us[j] = h;
                    a2l.us[j] = f2bf(ev[j] - bf2f(h));
                } else {
                    a2h.us[j] = (q == 2 && j == 0) ? (unsigned short)0x3F80 : (unsigned short)0;
                    a2l.us[j] = 0;
                }
            }
        }

        // stage 2T: ehT chunk c holds rows h = c*16 + q*4 + r, col = edge lo16
        float vch[4][4];
#pragma unroll
        for (int c = 0; c < 4; c++) {
            f32x4 c2 = {0.f, 0.f, 0.f, 0.f};
            c2 = __builtin_amdgcn_mfma_f32_16x16x32_bf16(w1h[c].v, a2h.v, c2, 0, 0, 0);
            c2 = __builtin_amdgcn_mfma_f32_16x16x32_bf16(w1l[c].v, a2h.v, c2, 0, 0, 0);
            c2 = __builtin_amdgcn_mfma_f32_16x16x32_bf16(w1h[c].v, a2l.v, c2, 0, 0, 0);
#pragma unroll
            for (int r = 0; r < 4; r++) vch[c][r] = fmaxf(c2[r], 0.f);
        }

        unsigned int dwH[4][2], dwL[4][2];
#pragma unroll
        for (int c = 0; c < 4; c++) {
#pragma unroll
            for (int d = 0; d < 2; d++) {
                float va = vch[c][2*d], vb = vch[c][2*d+1];
                unsigned short ha = f2bf(va), hb = f2bf(vb);
                dwH[c][d] = (unsigned int)ha | ((unsigned int)hb << 16);
                dwL[c][d] = pack2bf(va - bf2f(ha), vb - bf2f(hb));
            }
        }

        // pulls -> stage-3 B-frags: pull BOTH chunk candidates, select by q>>1
        BF8 b3h[2], b3l[2];
#pragma unroll
        for (int kb = 0; kb < 2; kb++) {
#pragma unroll
            for (int tt = 0; tt < 4; tt++) {
                int d = tt & 1;
                int addr = (tt >> 1) ? addrB : addrA;
                int h0 = __builtin_amdgcn_ds_bpermute(addr, (int)dwH[kb*2+0][d]);
                int h1 = __builtin_amdgcn_ds_bpermute(addr, (int)dwH[kb*2+1][d]);
                int l0 = __builtin_amdgcn_ds_bpermute(addr, (int)dwL[kb*2+0][d]);
                int l1 = __builtin_amdgcn_ds_bpermute(addr, (int)dwL[kb*2+1][d]);
                b3h[kb].ui[tt] = (unsigned int)(qhi1 ? h1 : h0);
                b3l[kb].ui[tt] = (unsigned int)(qhi1 ? l1 : l0);
            }
        }

        BF8 xT;
#pragma unroll
        for (int j = 0; j < 8; j++)
            xT.us[j] = qlow ? f2bf(xr[qc * 8 + j]) : (unsigned short)0;
        f32x4 msg = {0.f, 0.f, 0.f, 0.f};
        msg = __builtin_amdgcn_mfma_f32_16x16x32_bf16(be2T.v, xT.v, msg, 0, 0, 0);

#pragma unroll 4
        for (int mb = 0; mb < 16; mb++) {
            bf16x8 a3a = *(const bf16x8*)&a3[((mb * 2 + 0) * 64 + L) * 8];
            bf16x8 a3b = *(const bf16x8*)&a3[((mb * 2 + 1) * 64 + L) * 8];
            f32x4 acc = {0.f, 0.f, 0.f, 0.f};
            acc = __builtin_amdgcn_mfma_f32_16x16x32_bf16(a3a, b3h[0].v, acc, 0, 0, 0);
            acc = __builtin_amdgcn_mfma_f32_16x16x32_bf16(a3b, b3h[1].v, acc, 0, 0, 0);
            acc = __builtin_amdgcn_mfma_f32_16x16x32_bf16(a3a, b3l[0].v, acc, 0, 0, 0);
            acc = __builtin_amdgcn_mfma_f32_16x16x32_bf16(a3b, b3l[1].v, acc, 0, 0, 0);
            float xm = xr[mb];
            msg[0] += xm * acc[0];
            msg[1] += xm * acc[1];
            msg[2] += xm * acc[2];
            msg[3] += xm * acc[3];
        }

        float* np = neigh + (size_t)de * 16 + q * 4;
#pragma unroll
        for (int r = 0; r < 4; r++) atomicAdd(np + r, msg[r]);
    }
}

__device__ __forceinline__ void self_path(
    const float* __restrict__ h_self, const float* __restrict__ Wsf,
    float* __restrict__ y, float* __restrict__ bnacc,
    float (*red)[32], int t, int sb)
{
    int wv = t >> 6;
    int n = sb * 256 + t;
    bool act = (n < NN);
    float hv[16], yv[16];
    if (act) {
        const float4* h4 = (const float4*)(h_self + (size_t)n * 16);
#pragma unroll
        for (int k = 0; k < 4; k++) {
            float4 a = h4[k];
            hv[4*k+0] = a.x; hv[4*k+1] = a.y; hv[4*k+2] = a.z; hv[4*k+3] = a.w;
        }
    } else {
#pragma unroll
        for (int i = 0; i < 16; i++) hv[i] = 0.f;
    }
#pragma unroll
    for (int o = 0; o < 16; o++) {
        float a = 0.f;
#pragma unroll
        for (int i = 0; i < 16; i++) a += hv[i] * Wsf[i*16 + o];
        yv[o] = a;
    }
    if (act) {
        float4* y4 = (float4*)(y + (size_t)n * 16);
#pragma unroll
        for (int k = 0; k < 4; k++)
            y4[k] = make_float4(yv[4*k+0], yv[4*k+1], yv[4*k+2], yv[4*k+3]);
    }
    int lane = t & 63;
#pragma unroll
    for (int o = 0; o < 16; o++) {
        float a = act ? yv[o] : 0.f;
        float b = act ? yv[o]*yv[o] : 0.f;
#pragma unroll
        for (int off = 32; off > 0; off >>= 1) {
            a += __shfl_down(a, off);
            b += __shfl_down(b, off);
        }
        if (lane == 0) { red[wv][o] = a; red[wv][16 + o] = b; }
    }
    __syncthreads();
    if (t < 32) {
        float s = red[0][t] + red[1][t] + red[2][t] + red[3][t];
        atomicAdd(&bnacc[t], s);
    }
}

__device__ __forceinline__ void finalize_node(
    const float* __restrict__ y, const float* __restrict__ neigh,
    const float* __restrict__ bnacc, const float* __restrict__ gamma,
    const float* __restrict__ beta, float* __restrict__ out, int n)
{
    float z[16];
    float ss = 0.f;
    const float inv_n = 1.f / (float)NN;
#pragma unroll
    for (int o = 0; o < 16; o++) {
        float mu  = bnacc[o] * inv_n;
        float var = bnacc[16 + o] * inv_n - mu * mu;
        float inv = rsqrtf(var + BN_EPS);
        float yv  = (y[(size_t)n*16 + o] - mu) * inv * gamma[o] + beta[o];
        float tt  = tanhf(yv);
        float zz  = fmaxf(tt + neigh[(size_t)n*16 + o], 0.f);
        z[o] = zz;
        ss += zz * zz;
    }
    float nrm = sqrtf(ss);
    if (nrm == 0.f) nrm = 1.f;
    float r = 1.f / nrm;
#pragma unroll
    for (int o = 0; o < 16; o++) out[(size_t)n*16 + o] = z[o] * r;
}

// ====================== single fused cooperative kernel ======================
// LDS = 512 B only (A3 lives in global ws) so the cooperative co-residency
// check (uses ~64KB shared/CU) allows 4 blocks/CU -> grid 1024 is legal.
// r7 failed because 33 KB LDS capped the check at 256 blocks.
__global__ __launch_bounds__(256, 4) void fused_kernel(
    const float* __restrict__ h_neigh, const float* __restrict__ efeat,
    const int* __restrict__ src, const int* __restrict__ dst,
    const float* __restrict__ We1, const float* __restrict__ be1,
    const float* __restrict__ We2, const float* __restrict__ be2,
    float* __restrict__ neigh,
    const float* __restrict__ h_self, const float* __restrict__ Wsf,
    float* __restrict__ y, float* __restrict__ bnacc,
    unsigned short* __restrict__ a3g,
    const float* __restrict__ gamma, const float* __restrict__ beta,
    float* __restrict__ out)
{
    cg::grid_group grid = cg::this_grid();
    __shared__ float red[4][32];

    const int t = threadIdx.x;
    const int gtid = (int)blockIdx.x * 256 + t;

    // phase 0: zero accumulators + stage swizzled We2^T to global ws
    if (gtid < NN * 16 / 4) ((float4*)neigh)[gtid] = make_float4(0.f, 0.f, 0.f, 0.f);
    if (gtid < 32) bnacc[gtid] = 0.f;
    if (gtid < 4096) {
        const float4* W2v = (const float4*)We2;
        float4 w = W2v[gtid];
        int f = gtid * 4;
        int h = f >> 8, c = f & 255;
        int mb = c >> 4, kb = h >> 5, hh = h & 31, co = c & 15;
        int base = ((mb * 2 + kb) * 64 + (hh >> 3) * 16) * 8 + (hh & 7);
        a3g[base + (co + 0) * 8] = f2bf(w.x);
        a3g[base + (co + 1) * 8] = f2bf(w.y);
        a3g[base + (co + 2) * 8] = f2bf(w.z);
        a3g[base + (co + 3) * 8] = f2bf(w.w);
    }
    grid.sync();

    // phase 1: edge tiles (+ self path on blocks 945..1023)
    edge_tiles<const unsigned short*>(h_neigh, efeat, src, dst, We1, be1, be2,
                                      neigh, a3g, t, gridDim.x, blockIdx.x);
    int sb = (int)blockIdx.x - 945;
    if (sb >= 0 && sb < 79)
        self_path(h_self, Wsf, y, bnacc, red, t, sb);

    grid.sync();

    // phase 2: finalize
    if (gtid < NN)
        finalize_node(y, neigh, bnacc, gamma, beta, out, gtid);
}

// ====================== fallback path (r6 structure, 183 us) ======================
__global__ __launch_bounds__(256, 4) void edge_kernel_fb(
    const float* __restrict__ h_neigh, const float* __restrict__ efeat,
    const int* __restrict__ src, const int* __restrict__ dst,
    const float* __restrict__ We1, const float* __restrict__ be1,
    const float* __restrict__ We2, const float* __restrict__ be2,
    float* __restrict__ neigh,
    const float* __restrict__ h_self, const float* __restrict__ Wsf,
    float* __restrict__ y, float* __restrict__ bnacc)
{
    __shared__ __align__(16) unsigned short A3sw[16 * 2 * 64 * 8];
    __shared__ float red[4][32];
    const int t = threadIdx.x;
    {
        const float4* W2v = (const float4*)We2;
#pragma unroll
        for (int it = 0; it < 16; it++) {
            int c4 = t + 256 * it;
            float4 w = W2v[c4];
            int f = c4 * 4;
            int h = f >> 8, c = f & 255;
            int mb = c >> 4, kb = h >> 5, hh = h & 31, co = c & 15;
            int base = ((mb * 2 + kb) * 64 + (hh >> 3) * 16) * 8 + (hh & 7);
            A3sw[base + (co + 0) * 8] = f2bf(w.x);
            A3sw[base + (co + 1) * 8] = f2bf(w.y);
            A3sw[base + (co + 2) * 8] = f2bf(w.z);
            A3sw[base + (co + 3) * 8] = f2bf(w.w);
        }
    }
    __syncthreads();
    edge_tiles<const unsigned short*>(h_neigh, efeat, src, dst, We1, be1, be2,
                                      neigh, (const unsigned short*)A3sw,
                                      t, gridDim.x, blockIdx.x);
    int sb = (int)blockIdx.x - 945;
    if (sb >= 0 && sb < 79)
        self_path(h_self, Wsf, y, bnacc, red, t, sb);
}

__global__ __launch_bounds__(256) void final_kernel_fb(
    const float* __restrict__ y, const float* __restrict__ neigh,
    const float* __restrict__ bnacc, const float* __restrict__ gamma,
    const float* __restrict__ beta, float* __restrict__ out)
{
    int n = blockIdx.x * 256 + threadIdx.x;
    if (n < NN) finalize_node(y, neigh, bnacc, gamma, beta, out, n);
}

extern "C" void kernel_launch(void* const* d_in, const int* in_sizes, int n_in,
                              void* d_out, int out_size, void* d_ws, size_t ws_size,
                              hipStream_t stream) {
    const float* h_neigh = (const float*)d_in[0];
    const float* h_self  = (const float*)d_in[1];
    const float* efeat   = (const float*)d_in[2];
    const int*   src     = (const int*)d_in[3];
    const int*   dst     = (const int*)d_in[4];
    const float* W_self  = (const float*)d_in[5];
    const float* gamma   = (const float*)d_in[6];
    const float* beta    = (const float*)d_in[7];
    const float* We1     = (const float*)d_in[8];
    const float* be1     = (const float*)d_in[9];
    const float* We2     = (const float*)d_in[10];
    const float* be2     = (const float*)d_in[11];
    float* out = (float*)d_out;

    char* ws = (char*)d_ws;
    float* neigh = (float*)ws;
    float* bnacc = (float*)(ws + BNACC_OFF);
    float* y     = (float*)(ws + Y_OFF);
    unsigned short* a3g = (unsigned short*)(ws + A3_OFF);

    void* args[] = {
        (void*)&h_neigh, (void*)&efeat, (void*)&src, (void*)&dst,
        (void*)&We1, (void*)&be1, (void*)&We2, (void*)&be2,
        (void*)&neigh, (void*)&h_self, (void*)&W_self,
        (void*)&y, (void*)&bnacc, (void*)&a3g,
        (void*)&gamma, (void*)&beta, (void*)&out
    };
    hipError_t err = hipLaunchCooperativeKernel((void*)fused_kernel,
                                                dim3(1024), dim3(256),
                                                args, 0, stream);
    if (err != hipSuccess) {
        // fallback: proven r6 3-dispatch path
        hipMemsetAsync(d_ws, 0, Y_OFF, stream);
        edge_kernel_fb<<<1024, 256, 0, stream>>>(
            h_neigh, efeat, src, dst, We1, be1, We2, be2, neigh,
            h_self, W_self, y, bnacc);
        final_kernel_fb<<<(NN + 255)/256, 256, 0, stream>>>(
            y, neigh, bnacc, gamma, beta, out);
    }
}

// Round 10
// 258.732 us; speedup vs baseline: 1.4946x; 1.4946x over previous
//
#include <hip/hip_runtime.h>
#include <hip/hip_bf16.h>
#include <hip/hip_cooperative_groups.h>
#include <math.h>

namespace cg = cooperative_groups;

#define NN 20000
#define NE 320000
#define BN_EPS 1e-5f

// ws layout (fp32 neigh)
#define NEIGH_BYTES (NN * 16 * 4)              // 1,280,000
#define BNACC_OFF   NEIGH_BYTES
#define Y_OFF       (NEIGH_BYTES + 128)

typedef __bf16 bf16x8 __attribute__((ext_vector_type(8)));
typedef float  f32x4  __attribute__((ext_vector_type(4)));

union BF8 { bf16x8 v; unsigned short us[8]; unsigned int ui[4]; };

__device__ __forceinline__ unsigned short f2bf(float f) {
    unsigned int u = __builtin_bit_cast(unsigned int, f);
    u += 0x7FFFu + ((u >> 16) & 1u);   // RNE
    return (unsigned short)(u >> 16);
}
__device__ __forceinline__ float bf2f(unsigned short s) {
    unsigned int u = ((unsigned int)s) << 16;
    return __builtin_bit_cast(float, u);
}
__device__ __forceinline__ unsigned int pack2bf(float a, float b) {
    return (unsigned int)f2bf(a) | ((unsigned int)f2bf(b) << 16);
}

// ---- stage swizzled We2^T A-fragments into LDS (32 KB), NT = block threads
template <int NT>
__device__ __forceinline__ void stage_A3(const float* __restrict__ We2,
                                         unsigned short* __restrict__ A3sw, int t)
{
#pragma unroll
    for (int it = 0; it < 4096 / NT; it++) {
        int c4 = t + NT * it;               // 0..4095 float4 chunks
        float4 w = ((const float4*)We2)[c4];
        int f = c4 * 4;
        int h = f >> 8, c = f & 255;
        int mb = c >> 4, kb = h >> 5, hh = h & 31, co = c & 15;
        int base = ((mb * 2 + kb) * 64 + (hh >> 3) * 16) * 8 + (hh & 7);
        A3sw[base + (co + 0) * 8] = f2bf(w.x);
        A3sw[base + (co + 1) * 8] = f2bf(w.y);
        A3sw[base + (co + 2) * 8] = f2bf(w.z);
        A3sw[base + (co + 3) * 8] = f2bf(w.w);
    }
}

// Shared edge-tile worker (r6 math, verified absmax 1.03e-2).
// TILE_E = edges per block-tile (16 per wave).
template <int TILE_E>
__device__ __forceinline__ void edge_tiles(
    const float* __restrict__ h_neigh, const float* __restrict__ efeat,
    const int* __restrict__ src, const int* __restrict__ dst,
    const float* __restrict__ We1, const float* __restrict__ be1,
    const float* __restrict__ be2, float* __restrict__ neigh,
    const unsigned short* __restrict__ a3, int t, int nblocks, int myblock)
{
    const int L = t & 63, wv = t >> 6;
    const int lo16 = L & 15, q = L >> 4;
    const int qc = q & 1;
    const bool qlow = (q < 2);
    const bool qhi1 = ((q >> 1) != 0);   // target-side chunk select

    // We1^T A-frags (hi/lo) in registers, bias in K-padding slot k=16
    BF8 w1h[4], w1l[4];
#pragma unroll
    for (int c = 0; c < 4; c++) {
#pragma unroll
        for (int j = 0; j < 8; j++) {
            float w;
            if (q < 2)                 w = We1[(q * 8 + j) * 64 + c * 16 + lo16];
            else if (q == 2 && j == 0) w = be1[c * 16 + lo16];
            else                       w = 0.f;
            unsigned short h = f2bf(w);
            w1h[c].us[j] = h;
            w1l[c].us[j] = f2bf(w - bf2f(h));
        }
    }

    BF8 be2T;
#pragma unroll
    for (int j = 0; j < 8; j++) {
        float bv = be2[(qc * 8 + j) * 16 + lo16];
        be2T.us[j] = qlow ? f2bf(bv) : (unsigned short)0;
    }

    // bpermute source-lane byte addresses: src lane = ((q&1)*2 + (tt>>1))*16 + e
    const int addrA = (((q & 1) * 2 + 0) * 16 + lo16) * 4;
    const int addrB = (((q & 1) * 2 + 1) * 16 + lo16) * 4;

    for (int bt = myblock; bt < NE / TILE_E; bt += nblocks) {
        int e = bt * TILE_E + wv * 16 + lo16;
        int se = src[e];
        int de = dst[e];

        float xr[16];
        {
            const float4* xp = (const float4*)(h_neigh + (size_t)se * 16);
#pragma unroll
            for (int k4 = 0; k4 < 4; k4++) {
                float4 a = xp[k4];
                xr[k4*4+0] = a.x; xr[k4*4+1] = a.y; xr[k4*4+2] = a.z; xr[k4*4+3] = a.w;
            }
        }

        BF8 a2h, a2l;
        {
            const float4* ep = (const float4*)(efeat + (size_t)e * 16 + qc * 8);
            float4 e0 = ep[0], e1 = ep[1];
            float ev[8] = {e0.x, e0.y, e0.z, e0.w, e1.x, e1.y, e1.z, e1.w};
#pragma unroll
            for (int j = 0; j < 8; j++) {
                if (qlow) {
                    unsigned short h = f2bf(ev[j]);
                    a2h.us[j] = h;
                    a2l.us[j] = f2bf(ev[j] - bf2f(h));
                } else {
                    a2h.us[j] = (q == 2 && j == 0) ? (unsigned short)0x3F80 : (unsigned short)0;
                    a2l.us[j] = 0;
                }
            }
        }

        // stage 2T: ehT chunk c holds rows h = c*16 + q*4 + r, col = edge lo16
        float vch[4][4];
#pragma unroll
        for (int c = 0; c < 4; c++) {
            f32x4 c2 = {0.f, 0.f, 0.f, 0.f};
            c2 = __builtin_amdgcn_mfma_f32_16x16x32_bf16(w1h[c].v, a2h.v, c2, 0, 0, 0);
            c2 = __builtin_amdgcn_mfma_f32_16x16x32_bf16(w1l[c].v, a2h.v, c2, 0, 0, 0);
            c2 = __builtin_amdgcn_mfma_f32_16x16x32_bf16(w1h[c].v, a2l.v, c2, 0, 0, 0);
#pragma unroll
            for (int r = 0; r < 4; r++) vch[c][r] = fmaxf(c2[r], 0.f);
        }

        unsigned int dwH[4][2], dwL[4][2];
#pragma unroll
        for (int c = 0; c < 4; c++) {
#pragma unroll
            for (int d = 0; d < 2; d++) {
                float va = vch[c][2*d], vb = vch[c][2*d+1];
                unsigned short ha = f2bf(va), hb = f2bf(vb);
                dwH[c][d] = (unsigned int)ha | ((unsigned int)hb << 16);
                dwL[c][d] = pack2bf(va - bf2f(ha), vb - bf2f(hb));
            }
        }

        // pulls -> stage-3 B-frags: pull BOTH chunk candidates, select by q>>1
        BF8 b3h[2], b3l[2];
#pragma unroll
        for (int kb = 0; kb < 2; kb++) {
#pragma unroll
            for (int tt = 0; tt < 4; tt++) {
                int d = tt & 1;
                int addr = (tt >> 1) ? addrB : addrA;
                int h0 = __builtin_amdgcn_ds_bpermute(addr, (int)dwH[kb*2+0][d]);
                int h1 = __builtin_amdgcn_ds_bpermute(addr, (int)dwH[kb*2+1][d]);
                int l0 = __builtin_amdgcn_ds_bpermute(addr, (int)dwL[kb*2+0][d]);
                int l1 = __builtin_amdgcn_ds_bpermute(addr, (int)dwL[kb*2+1][d]);
                b3h[kb].ui[tt] = (unsigned int)(qhi1 ? h1 : h0);
                b3l[kb].ui[tt] = (unsigned int)(qhi1 ? l1 : l0);
            }
        }

        BF8 xT;
#pragma unroll
        for (int j = 0; j < 8; j++)
            xT.us[j] = qlow ? f2bf(xr[qc * 8 + j]) : (unsigned short)0;
        f32x4 msg = {0.f, 0.f, 0.f, 0.f};
        msg = __builtin_amdgcn_mfma_f32_16x16x32_bf16(be2T.v, xT.v, msg, 0, 0, 0);

#pragma unroll 4
        for (int mb = 0; mb < 16; mb++) {
            bf16x8 a3a = *(const bf16x8*)&a3[((mb * 2 + 0) * 64 + L) * 8];
            bf16x8 a3b = *(const bf16x8*)&a3[((mb * 2 + 1) * 64 + L) * 8];
            f32x4 acc = {0.f, 0.f, 0.f, 0.f};
            acc = __builtin_amdgcn_mfma_f32_16x16x32_bf16(a3a, b3h[0].v, acc, 0, 0, 0);
            acc = __builtin_amdgcn_mfma_f32_16x16x32_bf16(a3b, b3h[1].v, acc, 0, 0, 0);
            acc = __builtin_amdgcn_mfma_f32_16x16x32_bf16(a3a, b3l[0].v, acc, 0, 0, 0);
            acc = __builtin_amdgcn_mfma_f32_16x16x32_bf16(a3b, b3l[1].v, acc, 0, 0, 0);
            float xm = xr[mb];
            msg[0] += xm * acc[0];
            msg[1] += xm * acc[1];
            msg[2] += xm * acc[2];
            msg[3] += xm * acc[3];
        }

        float* np = neigh + (size_t)de * 16 + q * 4;
#pragma unroll
        for (int r = 0; r < 4; r++) atomicAdd(np + r, msg[r]);
    }
}

// NW = waves per block. Handles NT = NW*64 nodes starting at base.
template <int NW>
__device__ __forceinline__ void self_path(
    const float* __restrict__ h_self, const float* __restrict__ Wsf,
    float* __restrict__ y, float* __restrict__ bnacc,
    float (*red)[32], int t, int base)
{
    int wv = t >> 6;
    int n = base + t;
    bool act = (n < NN);
    float hv[16], yv[16];
    if (act) {
        const float4* h4 = (const float4*)(h_self + (size_t)n * 16);
#pragma unroll
        for (int k = 0; k < 4; k++) {
            float4 a = h4[k];
            hv[4*k+0] = a.x; hv[4*k+1] = a.y; hv[4*k+2] = a.z; hv[4*k+3] = a.w;
        }
    } else {
#pragma unroll
        for (int i = 0; i < 16; i++) hv[i] = 0.f;
    }
#pragma unroll
    for (int o = 0; o < 16; o++) {
        float a = 0.f;
#pragma unroll
        for (int i = 0; i < 16; i++) a += hv[i] * Wsf[i*16 + o];
        yv[o] = a;
    }
    if (act) {
        float4* y4 = (float4*)(y + (size_t)n * 16);
#pragma unroll
        for (int k = 0; k < 4; k++)
            y4[k] = make_float4(yv[4*k+0], yv[4*k+1], yv[4*k+2], yv[4*k+3]);
    }
    int lane = t & 63;
#pragma unroll
    for (int o = 0; o < 16; o++) {
        float a = act ? yv[o] : 0.f;
        float b = act ? yv[o]*yv[o] : 0.f;
#pragma unroll
        for (int off = 32; off > 0; off >>= 1) {
            a += __shfl_down(a, off);
            b += __shfl_down(b, off);
        }
        if (lane == 0) { red[wv][o] = a; red[wv][16 + o] = b; }
    }
    __syncthreads();
    if (t < 32) {
        float s = 0.f;
#pragma unroll
        for (int w = 0; w < NW; w++) s += red[w][t];
        atomicAdd(&bnacc[t], s);
    }
}

__device__ __forceinline__ void finalize_node(
    const float* __restrict__ y, const float* __restrict__ neigh,
    const float* __restrict__ bnacc, const float* __restrict__ gamma,
    const float* __restrict__ beta, float* __restrict__ out, int n)
{
    float z[16];
    float ss = 0.f;
    const float inv_n = 1.f / (float)NN;
#pragma unroll
    for (int o = 0; o < 16; o++) {
        float mu  = bnacc[o] * inv_n;
        float var = bnacc[16 + o] * inv_n - mu * mu;
        float inv = rsqrtf(var + BN_EPS);
        float yv  = (y[(size_t)n*16 + o] - mu) * inv * gamma[o] + beta[o];
        float tt  = tanhf(yv);
        float zz  = fmaxf(tt + neigh[(size_t)n*16 + o], 0.f);
        z[o] = zz;
        ss += zz * zz;
    }
    float nrm = sqrtf(ss);
    if (nrm == 0.f) nrm = 1.f;
    float r = 1.f / nrm;
#pragma unroll
    for (int o = 0; o < 16; o++) out[(size_t)n*16 + o] = z[o] * r;
}

// ====================== single fused cooperative kernel ======================
// 256 blocks x 1024 threads: the runtime's cooperative co-residency check uses
// ~64KB shared/CU, so 34KB LDS => 1 block/CU => <=256 blocks. 1024-thread
// blocks keep total waves at 16/CU (MORE latency hiding than r6's ~10) while
// A3 stays in LDS (r9 showed A3-in-global stalls everything: MfmaUtil 3.5%).
__global__ __launch_bounds__(1024, 4) void fused_kernel(
    const float* __restrict__ h_neigh, const float* __restrict__ efeat,
    const int* __restrict__ src, const int* __restrict__ dst,
    const float* __restrict__ We1, const float* __restrict__ be1,
    const float* __restrict__ We2, const float* __restrict__ be2,
    float* __restrict__ neigh,
    const float* __restrict__ h_self, const float* __restrict__ Wsf,
    float* __restrict__ y, float* __restrict__ bnacc,
    const float* __restrict__ gamma, const float* __restrict__ beta,
    float* __restrict__ out)
{
    cg::grid_group grid = cg::this_grid();
    __shared__ __align__(16) unsigned short A3sw[16 * 2 * 64 * 8];  // 32 KB
    __shared__ float red[16][32];                                    // 2 KB

    const int t = threadIdx.x;
    const int gtid = (int)blockIdx.x * 1024 + t;

    // phase 0: zero accumulators + stage A3 LDS
    if (gtid < NN * 16 / 4) ((float4*)neigh)[gtid] = make_float4(0.f, 0.f, 0.f, 0.f);
    if (gtid < 32) bnacc[gtid] = 0.f;
    stage_A3<1024>(We2, A3sw, t);
    __syncthreads();
    grid.sync();

    // phase 1: edge tiles (+ self path on blocks 236..255)
    edge_tiles<256>(h_neigh, efeat, src, dst, We1, be1, be2,
                    neigh, A3sw, t, gridDim.x, blockIdx.x);
    int sb = (int)blockIdx.x - 236;
    if (sb >= 0)
        self_path<16>(h_self, Wsf, y, bnacc, red, t, sb * 1024);

    grid.sync();

    // phase 2: finalize
    if (gtid < NN)
        finalize_node(y, neigh, bnacc, gamma, beta, out, gtid);
}

// ====================== fallback path (r6 structure, proven 183 us) ======================
__global__ __launch_bounds__(256, 4) void edge_kernel_fb(
    const float* __restrict__ h_neigh, const float* __restrict__ efeat,
    const int* __restrict__ src, const int* __restrict__ dst,
    const float* __restrict__ We1, const float* __restrict__ be1,
    const float* __restrict__ We2, const float* __restrict__ be2,
    float* __restrict__ neigh,
    const float* __restrict__ h_self, const float* __restrict__ Wsf,
    float* __restrict__ y, float* __restrict__ bnacc)
{
    __shared__ __align__(16) unsigned short A3sw[16 * 2 * 64 * 8];
    __shared__ float red[4][32];
    const int t = threadIdx.x;
    stage_A3<256>(We2, A3sw, t);
    __syncthreads();
    edge_tiles<64>(h_neigh, efeat, src, dst, We1, be1, be2,
                   neigh, A3sw, t, gridDim.x, blockIdx.x);
    int sb = (int)blockIdx.x - 945;
    if (sb >= 0 && sb < 79)
        self_path<4>(h_self, Wsf, y, bnacc, red, t, sb * 256);
}

__global__ __launch_bounds__(256) void final_kernel_fb(
    const float* __restrict__ y, const float* __restrict__ neigh,
    const float* __restrict__ bnacc, const float* __restrict__ gamma,
    const float* __restrict__ beta, float* __restrict__ out)
{
    int n = blockIdx.x * 256 + threadIdx.x;
    if (n < NN) finalize_node(y, neigh, bnacc, gamma, beta, out, n);
}

extern "C" void kernel_launch(void* const* d_in, const int* in_sizes, int n_in,
                              void* d_out, int out_size, void* d_ws, size_t ws_size,
                              hipStream_t stream) {
    const float* h_neigh = (const float*)d_in[0];
    const float* h_self  = (const float*)d_in[1];
    const float* efeat   = (const float*)d_in[2];
    const int*   src     = (const int*)d_in[3];
    const int*   dst     = (const int*)d_in[4];
    const float* W_self  = (const float*)d_in[5];
    const float* gamma   = (const float*)d_in[6];
    const float* beta    = (const float*)d_in[7];
    const float* We1     = (const float*)d_in[8];
    const float* be1     = (const float*)d_in[9];
    const float* We2     = (const float*)d_in[10];
    const float* be2     = (const float*)d_in[11];
    float* out = (float*)d_out;

    char* ws = (char*)d_ws;
    float* neigh = (float*)ws;
    float* bnacc = (float*)(ws + BNACC_OFF);
    float* y     = (float*)(ws + Y_OFF);

    void* args[] = {
        (void*)&h_neigh, (void*)&efeat, (void*)&src, (void*)&dst,
        (void*)&We1, (void*)&be1, (void*)&We2, (void*)&be2,
        (void*)&neigh, (void*)&h_self, (void*)&W_self,
        (void*)&y, (void*)&bnacc,
        (void*)&gamma, (void*)&beta, (void*)&out
    };
    hipError_t err = hipLaunchCooperativeKernel((void*)fused_kernel,
                                                dim3(256), dim3(1024),
                                                args, 0, stream);
    if (err != hipSuccess) {
        // fallback: proven r6 3-dispatch path
        hipMemsetAsync(d_ws, 0, Y_OFF, stream);
        edge_kernel_fb<<<1024, 256, 0, stream>>>(
            h_neigh, efeat, src, dst, We1, be1, We2, be2, neigh,
            h_self, W_self, y, bnacc);
        final_kernel_fb<<<(NN + 255)/256, 256, 0, stream>>>(
            y, neigh, bnacc, gamma, beta, out);
    }
}

// Round 11
// 209.796 us; speedup vs baseline: 1.8432x; 1.2333x over previous
//
#include <hip/hip_runtime.h>
#include <hip/hip_bf16.h>
#include <math.h>

#define NN 20000
#define NE 320000
#define BN_EPS 1e-5f

// ws layout (fp32 neigh)
#define NEIGH_BYTES (NN * 16 * 4)
#define BNACC_OFF   NEIGH_BYTES
#define Y_OFF       (NEIGH_BYTES + 128)

typedef __bf16 bf16x8 __attribute__((ext_vector_type(8)));
typedef float  f32x4  __attribute__((ext_vector_type(4)));

union BF8 { bf16x8 v; unsigned short us[8]; unsigned int ui[4]; };

__device__ __forceinline__ unsigned short f2bf(float f) {
    unsigned int u = __builtin_bit_cast(unsigned int, f);
    u += 0x7FFFu + ((u >> 16) & 1u);   // RNE
    return (unsigned short)(u >> 16);
}
__device__ __forceinline__ float bf2f(unsigned short s) {
    unsigned int u = ((unsigned int)s) << 16;
    return __builtin_bit_cast(float, u);
}
__device__ __forceinline__ unsigned int pack2bf(float a, float b) {
    return (unsigned int)f2bf(a) | ((unsigned int)f2bf(b) << 16);
}

// ---- stage swizzled We2^T A-fragments into LDS (32 KB)
__device__ __forceinline__ void stage_A3(const float* __restrict__ We2,
                                         unsigned short* __restrict__ A3sw, int t)
{
#pragma unroll
    for (int it = 0; it < 16; it++) {
        int c4 = t + 256 * it;               // 0..4095 float4 chunks
        float4 w = ((const float4*)We2)[c4];
        int f = c4 * 4;
        int h = f >> 8, c = f & 255;
        int mb = c >> 4, kb = h >> 5, hh = h & 31, co = c & 15;
        int base = ((mb * 2 + kb) * 64 + (hh >> 3) * 16) * 8 + (hh & 7);
        A3sw[base + (co + 0) * 8] = f2bf(w.x);
        A3sw[base + (co + 1) * 8] = f2bf(w.y);
        A3sw[base + (co + 2) * 8] = f2bf(w.z);
        A3sw[base + (co + 3) * 8] = f2bf(w.w);
    }
}

// ============================ edge path, DUAL-TILE ILP ============================
// r6 math (verified absmax 1.03e-2), but each wave processes TWO independent
// 16-edge groups per iteration: doubles loads/MFMA chains in flight (the r6
// profile showed no pipe >25% busy => latency-bound), and the A3 ds_read_b128s
// are shared by both groups (halves A3 LDS traffic + its bank conflicts).
__global__ __launch_bounds__(256, 3) void edge_kernel(
    const float* __restrict__ h_neigh, const float* __restrict__ efeat,
    const int* __restrict__ src, const int* __restrict__ dst,
    const float* __restrict__ We1, const float* __restrict__ be1,
    const float* __restrict__ We2, const float* __restrict__ be2,
    float* __restrict__ neigh,
    const float* __restrict__ h_self, const float* __restrict__ Wsf,
    float* __restrict__ y, float* __restrict__ bnacc)
{
    __shared__ __align__(16) unsigned short A3sw[16 * 2 * 64 * 8];  // 32 KB
    __shared__ float red[4][32];

    const int t = threadIdx.x;
    stage_A3(We2, A3sw, t);
    __syncthreads();

    const int L = t & 63, wv = t >> 6;
    const int lo16 = L & 15, q = L >> 4;
    const int qc = q & 1;
    const bool qlow = (q < 2);
    const bool qhi1 = ((q >> 1) != 0);   // target-side chunk select

    // We1^T A-frags (hi/lo) in registers, bias in K-padding slot k=16
    BF8 w1h[4], w1l[4];
#pragma unroll
    for (int c = 0; c < 4; c++) {
#pragma unroll
        for (int j = 0; j < 8; j++) {
            float w;
            if (q < 2)                 w = We1[(q * 8 + j) * 64 + c * 16 + lo16];
            else if (q == 2 && j == 0) w = be1[c * 16 + lo16];
            else                       w = 0.f;
            unsigned short h = f2bf(w);
            w1h[c].us[j] = h;
            w1l[c].us[j] = f2bf(w - bf2f(h));
        }
    }

    BF8 be2T;
#pragma unroll
    for (int j = 0; j < 8; j++) {
        float bv = be2[(qc * 8 + j) * 16 + lo16];
        be2T.us[j] = qlow ? f2bf(bv) : (unsigned short)0;
    }

    // bpermute source-lane byte addresses: src lane = ((q&1)*2 + (tt>>1))*16 + e
    const int addrA = (((q & 1) * 2 + 0) * 16 + lo16) * 4;
    const int addrB = (((q & 1) * 2 + 1) * 16 + lo16) * 4;

    // block-tile = 128 edges (4 waves x 32); grid-stride over NE/128 = 2500
    for (int bt = blockIdx.x; bt < NE / 128; bt += gridDim.x) {
        int e0 = bt * 128 + wv * 32 + lo16;   // group s: edge e0 + s*16
        int se[2], de[2];
#pragma unroll
        for (int s = 0; s < 2; s++) { se[s] = src[e0 + s*16]; de[s] = dst[e0 + s*16]; }

        float xr[2][16];
#pragma unroll
        for (int s = 0; s < 2; s++) {
            const float4* xp = (const float4*)(h_neigh + (size_t)se[s] * 16);
#pragma unroll
            for (int k4 = 0; k4 < 4; k4++) {
                float4 a = xp[k4];
                xr[s][k4*4+0] = a.x; xr[s][k4*4+1] = a.y;
                xr[s][k4*4+2] = a.z; xr[s][k4*4+3] = a.w;
            }
        }

        BF8 a2h[2], a2l[2];
#pragma unroll
        for (int s = 0; s < 2; s++) {
            const float4* ep = (const float4*)(efeat + (size_t)(e0 + s*16) * 16 + qc * 8);
            float4 ea = ep[0], eb = ep[1];
            float ev[8] = {ea.x, ea.y, ea.z, ea.w, eb.x, eb.y, eb.z, eb.w};
#pragma unroll
            for (int j = 0; j < 8; j++) {
                if (qlow) {
                    unsigned short h = f2bf(ev[j]);
                    a2h[s].us[j] = h;
                    a2l[s].us[j] = f2bf(ev[j] - bf2f(h));
                } else {
                    a2h[s].us[j] = (q == 2 && j == 0) ? (unsigned short)0x3F80 : (unsigned short)0;
                    a2l[s].us[j] = 0;
                }
            }
        }

        // stage 2T x2: independent MFMA chains
        float vch[2][4][4];
#pragma unroll
        for (int c = 0; c < 4; c++) {
#pragma unroll
            for (int s = 0; s < 2; s++) {
                f32x4 c2 = {0.f, 0.f, 0.f, 0.f};
                c2 = __builtin_amdgcn_mfma_f32_16x16x32_bf16(w1h[c].v, a2h[s].v, c2, 0, 0, 0);
                c2 = __builtin_amdgcn_mfma_f32_16x16x32_bf16(w1l[c].v, a2h[s].v, c2, 0, 0, 0);
                c2 = __builtin_amdgcn_mfma_f32_16x16x32_bf16(w1h[c].v, a2l[s].v, c2, 0, 0, 0);
#pragma unroll
                for (int r = 0; r < 4; r++) vch[s][c][r] = fmaxf(c2[r], 0.f);
            }
        }

        unsigned int dwH[2][4][2], dwL[2][4][2];
#pragma unroll
        for (int s = 0; s < 2; s++) {
#pragma unroll
            for (int c = 0; c < 4; c++) {
#pragma unroll
                for (int d = 0; d < 2; d++) {
                    float va = vch[s][c][2*d], vb = vch[s][c][2*d+1];
                    unsigned short ha = f2bf(va), hb = f2bf(vb);
                    dwH[s][c][d] = (unsigned int)ha | ((unsigned int)hb << 16);
                    dwL[s][c][d] = pack2bf(va - bf2f(ha), vb - bf2f(hb));
                }
            }
        }

        // pulls -> stage-3 B-frags (both chunk candidates, select by q>>1)
        BF8 b3h[2][2], b3l[2][2];
#pragma unroll
        for (int s = 0; s < 2; s++) {
#pragma unroll
            for (int kb = 0; kb < 2; kb++) {
#pragma unroll
                for (int tt = 0; tt < 4; tt++) {
                    int d = tt & 1;
                    int addr = (tt >> 1) ? addrB : addrA;
                    int h0 = __builtin_amdgcn_ds_bpermute(addr, (int)dwH[s][kb*2+0][d]);
                    int h1 = __builtin_amdgcn_ds_bpermute(addr, (int)dwH[s][kb*2+1][d]);
                    int l0 = __builtin_amdgcn_ds_bpermute(addr, (int)dwL[s][kb*2+0][d]);
                    int l1 = __builtin_amdgcn_ds_bpermute(addr, (int)dwL[s][kb*2+1][d]);
                    b3h[s][kb].ui[tt] = (unsigned int)(qhi1 ? h1 : h0);
                    b3l[s][kb].ui[tt] = (unsigned int)(qhi1 ? l1 : l0);
                }
            }
        }

        // be2 term x2
        f32x4 msg[2];
#pragma unroll
        for (int s = 0; s < 2; s++) {
            BF8 xT;
#pragma unroll
            for (int j = 0; j < 8; j++)
                xT.us[j] = qlow ? f2bf(xr[s][qc * 8 + j]) : (unsigned short)0;
            f32x4 m = {0.f, 0.f, 0.f, 0.f};
            msg[s] = __builtin_amdgcn_mfma_f32_16x16x32_bf16(be2T.v, xT.v, m, 0, 0, 0);
        }

        // stage 3: one A3 read pair serves BOTH groups (8 MFMA per mb)
#pragma unroll 4
        for (int mb = 0; mb < 16; mb++) {
            bf16x8 a3a = *(const bf16x8*)&A3sw[((mb * 2 + 0) * 64 + L) * 8];
            bf16x8 a3b = *(const bf16x8*)&A3sw[((mb * 2 + 1) * 64 + L) * 8];
#pragma unroll
            for (int s = 0; s < 2; s++) {
                f32x4 acc = {0.f, 0.f, 0.f, 0.f};
                acc = __builtin_amdgcn_mfma_f32_16x16x32_bf16(a3a, b3h[s][0].v, acc, 0, 0, 0);
                acc = __builtin_amdgcn_mfma_f32_16x16x32_bf16(a3b, b3h[s][1].v, acc, 0, 0, 0);
                acc = __builtin_amdgcn_mfma_f32_16x16x32_bf16(a3a, b3l[s][0].v, acc, 0, 0, 0);
                acc = __builtin_amdgcn_mfma_f32_16x16x32_bf16(a3b, b3l[s][1].v, acc, 0, 0, 0);
                float xm = xr[s][mb];
                msg[s][0] += xm * acc[0];
                msg[s][1] += xm * acc[1];
                msg[s][2] += xm * acc[2];
                msg[s][3] += xm * acc[3];
            }
        }

#pragma unroll
        for (int s = 0; s < 2; s++) {
            float* np = neigh + (size_t)de[s] * 16 + q * 4;
#pragma unroll
            for (int r = 0; r < 4; r++) atomicAdd(np + r, msg[s][r]);
        }
    }

    // ---------------- fused self path (blocks 945..1023) ----------------
    int sb = (int)blockIdx.x - 945;
    if (sb >= 0 && sb < 79) {
        int n = sb * 256 + t;
        bool act = (n < NN);
        float hv[16], yv[16];
        if (act) {
            const float4* h4 = (const float4*)(h_self + (size_t)n * 16);
#pragma unroll
            for (int k = 0; k < 4; k++) {
                float4 a = h4[k];
                hv[4*k+0] = a.x; hv[4*k+1] = a.y; hv[4*k+2] = a.z; hv[4*k+3] = a.w;
            }
        } else {
#pragma unroll
            for (int i = 0; i < 16; i++) hv[i] = 0.f;
        }
#pragma unroll
        for (int o = 0; o < 16; o++) {
            float a = 0.f;
#pragma unroll
            for (int i = 0; i < 16; i++) a += hv[i] * Wsf[i*16 + o];
            yv[o] = a;
        }
        if (act) {
            float4* y4 = (float4*)(y + (size_t)n * 16);
#pragma unroll
            for (int k = 0; k < 4; k++)
                y4[k] = make_float4(yv[4*k+0], yv[4*k+1], yv[4*k+2], yv[4*k+3]);
        }
        int lane = t & 63;
#pragma unroll
        for (int o = 0; o < 16; o++) {
            float a = act ? yv[o] : 0.f;
            float b = act ? yv[o]*yv[o] : 0.f;
#pragma unroll
            for (int off = 32; off > 0; off >>= 1) {
                a += __shfl_down(a, off);
                b += __shfl_down(b, off);
            }
            if (lane == 0) { red[wv][o] = a; red[wv][16 + o] = b; }
        }
        __syncthreads();
        if (t < 32) {
            float s = red[0][t] + red[1][t] + red[2][t] + red[3][t];
            atomicAdd(&bnacc[t], s);
        }
    }
}

// ---- finalize: BN + tanh + add + relu + L2-normalize ----
__global__ __launch_bounds__(256) void final_kernel(
    const float* __restrict__ y, const float* __restrict__ neigh,
    const float* __restrict__ bnacc, const float* __restrict__ gamma,
    const float* __restrict__ beta, float* __restrict__ out)
{
    int n = blockIdx.x * 256 + threadIdx.x;
    if (n >= NN) return;
    float z[16];
    float ss = 0.f;
    const float inv_n = 1.f / (float)NN;
#pragma unroll
    for (int o = 0; o < 16; o++) {
        float mu  = bnacc[o] * inv_n;
        float var = bnacc[16 + o] * inv_n - mu * mu;
        float inv = rsqrtf(var + BN_EPS);
        float yv  = (y[(size_t)n*16 + o] - mu) * inv * gamma[o] + beta[o];
        float tt  = tanhf(yv);
        float zz  = fmaxf(tt + neigh[(size_t)n*16 + o], 0.f);
        z[o] = zz;
        ss += zz * zz;
    }
    float nrm = sqrtf(ss);
    if (nrm == 0.f) nrm = 1.f;
    float r = 1.f / nrm;
#pragma unroll
    for (int o = 0; o < 16; o++) out[(size_t)n*16 + o] = z[o] * r;
}

extern "C" void kernel_launch(void* const* d_in, const int* in_sizes, int n_in,
                              void* d_out, int out_size, void* d_ws, size_t ws_size,
                              hipStream_t stream) {
    const float* h_neigh = (const float*)d_in[0];
    const float* h_self  = (const float*)d_in[1];
    const float* efeat   = (const float*)d_in[2];
    const int*   src     = (const int*)d_in[3];
    const int*   dst     = (const int*)d_in[4];
    const float* W_self  = (const float*)d_in[5];
    const float* gamma   = (const float*)d_in[6];
    const float* beta    = (const float*)d_in[7];
    const float* We1     = (const float*)d_in[8];
    const float* be1     = (const float*)d_in[9];
    const float* We2     = (const float*)d_in[10];
    const float* be2     = (const float*)d_in[11];
    float* out = (float*)d_out;

    char* ws = (char*)d_ws;
    float* neigh = (float*)ws;
    float* bnacc = (float*)(ws + BNACC_OFF);
    float* y     = (float*)(ws + Y_OFF);

    // zero neigh + BN accumulators (ws poisoned 0xAA each call)
    hipMemsetAsync(d_ws, 0, Y_OFF, stream);

    edge_kernel<<<1024, 256, 0, stream>>>(
        h_neigh, efeat, src, dst, We1, be1, We2, be2, neigh,
        h_self, W_self, y, bnacc);
    final_kernel<<<(NN + 255)/256, 256, 0, stream>>>(y, neigh, bnacc, gamma, beta, out);
}